// Round 6
// baseline (190.096 us; speedup 1.0000x reference)
//
#include <hip/hip_runtime.h>
#include <math.h>

#define BB 4
#define LL 4096
#define DD 256
#define NROWS (BB*LL)      // 16384
#define CHUNK 32
#define NC (LL/CHUNK)      // 128

typedef __bf16 bf16x8 __attribute__((ext_vector_type(8)));
typedef __bf16 bf16x4 __attribute__((ext_vector_type(4)));
typedef float floatx4 __attribute__((ext_vector_type(4)));
typedef unsigned long long u64;

// ordered-uint encoding for float compare/minmax (monotone map)
__device__ __forceinline__ unsigned encf(float f) {
    unsigned u = __float_as_uint(f);
    return (u & 0x80000000u) ? ~u : (u | 0x80000000u);
}
__device__ __forceinline__ float decf(unsigned u) {
    return __uint_as_float((u & 0x80000000u) ? (u ^ 0x80000000u) : ~u);
}

// ---------------- K1: partial u = {Wq^T w, Wk^T w} + split Wv + hdru init ----------------
__global__ void k_prep(const float* __restrict__ Wq, const float* __restrict__ Wk,
                       const float* __restrict__ Wv, const float* __restrict__ w,
                       float* __restrict__ u_part,
                       __bf16* __restrict__ Wh, __bf16* __restrict__ Wl,
                       unsigned* __restrict__ hdru) {
    __shared__ float wl[16];
    int d = threadIdx.x;
    int e0 = blockIdx.x * 16;
    if (blockIdx.x == 0 && d < 8) hdru[d] = (d & 1) ? 0u : 0xFFFFFFFFu;  // [min,max] per batch
    if (d < 16) wl[d] = w[e0 + d];
    __syncthreads();
    float aq = 0.f, ak = 0.f;
    #pragma unroll
    for (int j = 0; j < 16; ++j) {
        float we = wl[j];
        aq = fmaf(Wq[(size_t)(e0 + j)*DD + d], we, aq);
        ak = fmaf(Wk[(size_t)(e0 + j)*DD + d], we, ak);
        float wv = Wv[(size_t)(e0 + j)*DD + d];
        __bf16 h = (__bf16)wv;
        Wh[(size_t)(e0 + j)*DD + d] = h;
        Wl[(size_t)(e0 + j)*DD + d] = (__bf16)(wv - (float)h);
    }
    u_part[(size_t)blockIdx.x*512 + d]       = aq;
    u_part[(size_t)blockIdx.x*512 + DD + d]  = ak;
}

// ---------------- K2: V = x @ Wv^T via split-bf16 MFMA (r2-verified core) ----------------
// Epilogue: a (+bias), u64 keys for c and a (ordered-uint<<32 | idx), c min/max atomics.
__global__ void __launch_bounds__(256) k_gemm_mfma(
        const float* __restrict__ x,
        const __bf16* __restrict__ Wh, const __bf16* __restrict__ Wl,
        const float* __restrict__ u_part, const float* __restrict__ bmlp,
        float* __restrict__ V, float* __restrict__ a,
        u64* __restrict__ ckeys, u64* __restrict__ akeys,
        unsigned* __restrict__ hdru) {
    __shared__ __bf16 Ah[2][32*40];
    __shared__ __bf16 Al[2][32*40];
    __shared__ float4 ul[128];
    __shared__ float pros[512];
    const int tid = threadIdx.x;
    const int wave = tid >> 6, lane = tid & 63;
    const int rowBase = blockIdx.x * 32;
    const int colBase = blockIdx.y * 128;
    const int quad = lane >> 4, l16 = lane & 15;
    const int srow = tid >> 3, skq = (tid & 7) * 4;
    const bool doproj = (blockIdx.y == 0);

    if (doproj && tid < 128) {
        float4 s = make_float4(0.f, 0.f, 0.f, 0.f);
        #pragma unroll
        for (int g = 0; g < 16; ++g) {
            float4 p = *(const float4*)(u_part + (size_t)g*512 + tid*4);
            s.x += p.x; s.y += p.y; s.z += p.z; s.w += p.w;
        }
        ul[tid] = s;
    }
    __syncthreads();

    floatx4 acc[2][2];
    #pragma unroll
    for (int rt = 0; rt < 2; ++rt)
        #pragma unroll
        for (int ct = 0; ct < 2; ++ct)
            acc[rt][ct] = (floatx4){0.f, 0.f, 0.f, 0.f};
    float aq = 0.f, ak = 0.f;

    const float* xrow = x + (size_t)(rowBase + srow)*DD + skq;

    {
        float4 xv = *(const float4*)xrow;
        __bf16 h0 = (__bf16)xv.x, h1 = (__bf16)xv.y, h2 = (__bf16)xv.z, h3 = (__bf16)xv.w;
        bf16x4 hv = {h0, h1, h2, h3};
        bf16x4 lv = {(__bf16)(xv.x - (float)h0), (__bf16)(xv.y - (float)h1),
                     (__bf16)(xv.z - (float)h2), (__bf16)(xv.w - (float)h3)};
        *(bf16x4*)&Ah[0][srow*40 + skq] = hv;
        *(bf16x4*)&Al[0][srow*40 + skq] = lv;
        if (doproj) {
            float4 q4 = ul[(tid & 7)];
            float4 k4 = ul[64 + (tid & 7)];
            aq = fmaf(xv.x, q4.x, fmaf(xv.y, q4.y, fmaf(xv.z, q4.z, fmaf(xv.w, q4.w, aq))));
            ak = fmaf(xv.x, k4.x, fmaf(xv.y, k4.y, fmaf(xv.z, k4.z, fmaf(xv.w, k4.w, ak))));
        }
    }
    __syncthreads();

    for (int t = 0; t < 8; ++t) {
        const int k0 = t * 32;
        const int cur = t & 1;
        float4 xv;
        if (t < 7) xv = *(const float4*)(xrow + k0 + 32);
        bf16x8 ah[2], al[2];
        #pragma unroll
        for (int rt = 0; rt < 2; ++rt) {
            int m = rt*16 + l16;
            ah[rt] = *(bf16x8*)&Ah[cur][m*40 + quad*8];
            al[rt] = *(bf16x8*)&Al[cur][m*40 + quad*8];
        }
        if (t < 7) {
            __bf16 h0 = (__bf16)xv.x, h1 = (__bf16)xv.y, h2 = (__bf16)xv.z, h3 = (__bf16)xv.w;
            bf16x4 hv = {h0, h1, h2, h3};
            bf16x4 lv = {(__bf16)(xv.x - (float)h0), (__bf16)(xv.y - (float)h1),
                         (__bf16)(xv.z - (float)h2), (__bf16)(xv.w - (float)h3)};
            *(bf16x4*)&Ah[cur^1][srow*40 + skq] = hv;
            *(bf16x4*)&Al[cur^1][srow*40 + skq] = lv;
            if (doproj) {
                float4 q4 = ul[((k0 + 32) >> 2) + (tid & 7)];
                float4 k4 = ul[64 + ((k0 + 32) >> 2) + (tid & 7)];
                aq = fmaf(xv.x, q4.x, fmaf(xv.y, q4.y, fmaf(xv.z, q4.z, fmaf(xv.w, q4.w, aq))));
                ak = fmaf(xv.x, k4.x, fmaf(xv.y, k4.y, fmaf(xv.z, k4.z, fmaf(xv.w, k4.w, ak))));
            }
        }
        __syncthreads();
        #pragma unroll
        for (int ct = 0; ct < 2; ++ct) {
            int n = colBase + wave*32 + ct*16 + l16;
            bf16x8 bh = *(const bf16x8*)(Wh + (size_t)n*DD + k0 + quad*8);
            bf16x8 bl = *(const bf16x8*)(Wl + (size_t)n*DD + k0 + quad*8);
            #pragma unroll
            for (int rt = 0; rt < 2; ++rt) {
                acc[rt][ct] = __builtin_amdgcn_mfma_f32_16x16x32_bf16(ah[rt], bh, acc[rt][ct], 0, 0, 0);
                acc[rt][ct] = __builtin_amdgcn_mfma_f32_16x16x32_bf16(ah[rt], bl, acc[rt][ct], 0, 0, 0);
                acc[rt][ct] = __builtin_amdgcn_mfma_f32_16x16x32_bf16(al[rt], bh, acc[rt][ct], 0, 0, 0);
            }
        }
    }
    #pragma unroll
    for (int rt = 0; rt < 2; ++rt)
        #pragma unroll
        for (int ct = 0; ct < 2; ++ct)
            #pragma unroll
            for (int i = 0; i < 4; ++i) {
                int row = rowBase + rt*16 + quad*4 + i;
                int col = colBase + wave*32 + ct*16 + l16;
                V[(size_t)row*DD + col] = acc[rt][ct][i];
            }
    if (doproj) {
        __syncthreads();
        pros[tid] = aq;
        pros[256 + tid] = ak;
        __syncthreads();
        if (tid < 32) {
            float sa = 0.f, sc = 0.f;
            #pragma unroll
            for (int j = 0; j < 8; ++j) {
                sa += pros[tid*8 + j];
                sc += pros[256 + tid*8 + j];
            }
            int grow = rowBase + tid;          // global row == b*LL + l
            float av = sa + bmlp[0];
            a[grow] = av;
            ckeys[grow] = ((u64)encf(sc) << 32) | (unsigned)(grow & (LL-1));
            akeys[grow] = ((u64)encf(av) << 32);
            // batch-wide c min/max (exact, order-invariant) via ordered-uint atomics
            float mn = sc, mx = sc;
            #pragma unroll
            for (int off = 16; off > 0; off >>= 1) {
                mn = fminf(mn, __shfl_down(mn, off));
                mx = fmaxf(mx, __shfl_down(mx, off));
            }
            if (tid == 0) {
                int bb = rowBase >> 12;
                atomicMin(&hdru[bb*2 + 0], encf(mn));
                atomicMax(&hdru[bb*2 + 1], encf(mx));
            }
        }
    }
}

// ---------------- K3: exact ranks by brute-force counting (replaces the sort) ----------------
// 8192 queries per batch: g<LL -> element j=g (rank in c-order, tie-broken by index);
// g>=LL -> row i=g-LL (k_i = #{c_m < a_i}). 16 threads per query, each counts a
// 256-key interleaved slice (m = t + 16s: lanes coalesce), shfl-reduce width 16.
// Deterministic, no atomics, 2048 blocks.
__global__ void __launch_bounds__(256) k_rank(
        const u64* __restrict__ ckeys, const u64* __restrict__ akeys,
        const unsigned* __restrict__ hdru,
        int* __restrict__ perm, float* __restrict__ e_sorted,
        int* __restrict__ rowk)
{
    const int b = blockIdx.y, tid = threadIdx.x;
    const int ql = tid >> 4, t = tid & 15;
    const int g = blockIdx.x * 16 + ql;             // 0..8191
    const u64* kb = ckeys + (size_t)b*LL;
    const u64 K = (g < LL) ? kb[g] : akeys[(size_t)b*LL + (g - LL)];
    int cnt = 0;
    #pragma unroll 16
    for (int s = 0; s < 256; ++s) {
        u64 km = kb[t + (s << 4)];
        cnt += (km < K) ? 1 : 0;
    }
    cnt += __shfl_down(cnt, 8, 16);
    cnt += __shfl_down(cnt, 4, 16);
    cnt += __shfl_down(cnt, 2, 16);
    cnt += __shfl_down(cnt, 1, 16);
    if (t == 0) {
        if (g < LL) {
            float cj = decf((unsigned)(K >> 32));
            float cmin = decf(hdru[b*2]);
            perm[(size_t)b*LL + cnt] = g;
            e_sorted[(size_t)b*LL + cnt] = expf(cmin - cj);
        } else {
            rowk[(size_t)b*LL + (g - LL)] = cnt;
        }
    }
}

// ---------------- K4: merged SE-scan (blocks 0..3) + chunked V prefix (blocks 4..131) ----------------
// Both roles depend only on k_rank outputs -> concurrent in one dispatch.
// Scan role is r0's verified k_scan (CHUNK=32, Pl/Pel/Tp/Te), 4 chunks per 1024-thr block.
__global__ void __launch_bounds__(1024) k_mid(
        const int* __restrict__ perm, const float* __restrict__ e_sorted,
        const float* __restrict__ V,
        float* __restrict__ SE,
        float* __restrict__ Pl, float* __restrict__ Pel,
        float* __restrict__ Tp, float* __restrict__ Te)
{
    __shared__ float scrf[64];
    __shared__ int   pj_l[4][CHUNK];
    __shared__ float pe_l[4][CHUNK];
    const int bid = blockIdx.x, tid = threadIdx.x;
    if (bid < BB) {
        // ---- SE role: exclusive prefix of e_sorted over ranks (r0 math) ----
        const int b = bid, wave = tid >> 6, lane = tid & 63;
        float4 ev = ((const float4*)(e_sorted + (size_t)b*LL))[tid];
        float ew[4] = {ev.x, ev.y, ev.z, ev.w};
        float le[4]; float s0 = 0.f;
        #pragma unroll
        for (int u = 0; u < 4; ++u) { le[u] = s0; s0 += ew[u]; }
        float fincl = s0;
        #pragma unroll
        for (int off = 1; off < 64; off <<= 1) {
            float tt = __shfl_up(fincl, off);
            if (lane >= off) fincl += tt;
        }
        if (lane == 63) scrf[wave] = fincl;
        __syncthreads();
        if (wave == 0) {
            float v = (lane < 16) ? scrf[lane] : 0.f;
            float s = v;
            #pragma unroll
            for (int off = 1; off < 16; off <<= 1) {
                float tt = __shfl_up(s, off);
                if (lane >= off) s += tt;
            }
            if (lane < 16) scrf[lane] = s - v;
        }
        __syncthreads();
        float texcl = (fincl - s0) + scrf[wave];
        #pragma unroll
        for (int u = 0; u < 4; ++u)
            SE[(size_t)b*(LL+1) + tid*4 + u] = texcl + le[u];
        if (tid == 1023) SE[(size_t)b*(LL+1) + LL] = texcl + s0;
    } else {
        // ---- scan role: 4 chunks per block ----
        const int task = bid - BB;              // 0..127
        const int sub = tid >> 8, d = tid & 255;
        const int chunk = task*4 + sub;         // 0..511
        const int b = chunk >> 7, q = chunk & (NC-1);
        if (d < CHUNK) {
            pj_l[sub][d] = perm[(size_t)b*LL + q*CHUNK + d];
            pe_l[sub][d] = e_sorted[(size_t)b*LL + q*CHUNK + d];
        }
        __syncthreads();
        float vr[CHUNK];
        #pragma unroll
        for (int r = 0; r < CHUNK; ++r)
            vr[r] = V[((size_t)b*LL + pj_l[sub][r])*DD + d];
        float acc = 0.f, acce = 0.f;
        size_t kb = (size_t)b*LL + (size_t)q*CHUNK;
        #pragma unroll
        for (int r = 0; r < CHUNK; ++r) {
            size_t o = (kb + r)*DD + d;
            Pl[o]  = acc;
            Pel[o] = acce;
            acc += vr[r];
            acce = fmaf(pe_l[sub][r], vr[r], acce);
        }
        size_t to = ((size_t)b*NC + q)*DD + d;
        Tp[to] = acc;
        Te[to] = acce;
    }
}

// ---------------- K5: chunk bases (r0 exact) ----------------
__global__ void k_base(const float* __restrict__ Tp, const float* __restrict__ Te,
        float* __restrict__ baseP, float* __restrict__ basePe) {
    int q = blockIdx.x, b = blockIdx.y, d = threadIdx.x;
    float acc = 0.f, acce = 0.f;
    #pragma unroll 8
    for (int i = 0; i < q; ++i) {
        size_t ti = ((size_t)b*NC + i) * DD + d;
        acc += Tp[ti]; acce += Te[ti];
    }
    size_t o = ((size_t)b*(NC+1) + q) * DD + d;
    baseP[o] = acc; basePe[o] = acce;
}

// ---------------- K6: per-row output, exact k -> pure O(1), no boundary loop ----------------
__global__ void k_out(const float* __restrict__ a, const unsigned* __restrict__ hdru,
                      const int* __restrict__ rowk,
                      const float* __restrict__ SE,
                      const float* __restrict__ Pl, const float* __restrict__ Pel,
                      const float* __restrict__ baseP, const float* __restrict__ basePe,
                      float* __restrict__ out) {
    int row = blockIdx.x * 4 + (threadIdx.x >> 6);
    int lane = threadIdx.x & 63;
    int b = row >> 12;
    float ai = a[row];
    float cmin = decf(hdru[b*2]);
    int k = rowk[row];
    float alpha = expf(cmin - ai);
    float Z = fmaf(alpha, (float)(LL - k), SE[(size_t)b*(LL+1) + k]);
    size_t db = (size_t)lane * 4;
    size_t totoff = ((size_t)b * (NC+1) + NC) * DD + db;
    float4 ptot = *(const float4*)(baseP + totoff);
    float4 pk, pek;
    if (k < LL) {
        int q = k >> 5;
        size_t po = ((size_t)b * LL + k) * DD + db;
        size_t bo = ((size_t)b * (NC+1) + q) * DD + db;
        float4 pl = *(const float4*)(Pl    + po);
        float4 bp = *(const float4*)(baseP + bo);
        float4 pe = *(const float4*)(Pel    + po);
        float4 be = *(const float4*)(basePe + bo);
        pk.x = pl.x + bp.x; pk.y = pl.y + bp.y; pk.z = pl.z + bp.z; pk.w = pl.w + bp.w;
        pek.x = pe.x + be.x; pek.y = pe.y + be.y; pek.z = pe.z + be.z; pek.w = pe.w + be.w;
    } else {
        pk = ptot;
        pek = *(const float4*)(basePe + totoff);
    }
    float4 num;
    num.x = fmaf(alpha, ptot.x - pk.x, pek.x);
    num.y = fmaf(alpha, ptot.y - pk.y, pek.y);
    num.z = fmaf(alpha, ptot.z - pk.z, pek.z);
    num.w = fmaf(alpha, ptot.w - pk.w, pek.w);
    float invZ = 1.f / Z;
    float4 o;
    o.x = num.x * invZ; o.y = num.y * invZ; o.z = num.z * invZ; o.w = num.w * invZ;
    *(float4*)(out + (size_t)row * DD + db) = o;
}

extern "C" void kernel_launch(void* const* d_in, const int* in_sizes, int n_in,
                              void* d_out, int out_size, void* d_ws, size_t ws_size,
                              hipStream_t stream) {
    const float* x  = (const float*)d_in[0];
    const float* Wq = (const float*)d_in[1];
    const float* Wk = (const float*)d_in[2];
    const float* Wv = (const float*)d_in[3];
    const float* wm = (const float*)d_in[4];
    const float* bm = (const float*)d_in[5];
    float* out = (float*)d_out;
    float* ws = (float*)d_ws;

    size_t off = 0;
    auto alloc = [&](size_t n) {      // n in floats
        float* p = ws + off;
        off += (n + 255) & ~(size_t)255;
        return p;
    };
    float* u_part   = alloc(16*512);
    float* a        = alloc(NROWS);
    float* e_sorted = alloc(NROWS);
    float* SE       = alloc((size_t)BB*(LL+1));
    int*   perm     = (int*)alloc(NROWS);
    int*   rowk     = (int*)alloc(NROWS);
    unsigned* hdru  = (unsigned*)alloc(2*BB);
    float* V        = alloc((size_t)NROWS*DD);
    float* Pl       = alloc((size_t)NROWS*DD);
    float* Pel      = alloc((size_t)NROWS*DD);
    float* Tp       = alloc((size_t)BB*NC*DD);
    float* Te       = alloc((size_t)BB*NC*DD);
    float* baseP    = alloc((size_t)BB*(NC+1)*DD);
    float* basePe   = alloc((size_t)BB*(NC+1)*DD);
    u64*   ckeys    = (u64*)alloc((size_t)NROWS*2);
    u64*   akeys    = (u64*)alloc((size_t)NROWS*2);
    __bf16* Wh      = (__bf16*)alloc((size_t)DD*DD/2);
    __bf16* Wl      = (__bf16*)alloc((size_t)DD*DD/2);

    hipLaunchKernelGGL(k_prep, dim3(16), dim3(DD), 0, stream,
                       Wq, Wk, Wv, wm, u_part, Wh, Wl, hdru);
    hipLaunchKernelGGL(k_gemm_mfma, dim3(NROWS/32, 2), dim3(256), 0, stream,
                       x, Wh, Wl, u_part, bm, V, a, ckeys, akeys, hdru);
    hipLaunchKernelGGL(k_rank, dim3(512, BB), dim3(256), 0, stream,
                       ckeys, akeys, hdru, perm, e_sorted, rowk);
    hipLaunchKernelGGL(k_mid, dim3(BB + NC*BB/4), dim3(1024), 0, stream,
                       perm, e_sorted, V, SE, Pl, Pel, Tp, Te);
    hipLaunchKernelGGL(k_base, dim3(NC+1, BB), dim3(256), 0, stream,
                       Tp, Te, baseP, basePe);
    hipLaunchKernelGGL(k_out, dim3(NROWS/4), dim3(256), 0, stream,
                       a, hdru, rowk, SE, Pl, Pel, baseP, basePe, out);
}

// Round 7
// 151.298 us; speedup vs baseline: 1.2564x; 1.2564x over previous
//
#include <hip/hip_runtime.h>
#include <math.h>

#define BB 4
#define LL 4096
#define DD 256
#define NROWS (BB*LL)      // 16384
#define CHUNK 32
#define NC (LL/CHUNK)      // 128
#define NB 8192            // counting-sort bins

typedef __bf16 bf16x8 __attribute__((ext_vector_type(8)));
typedef __bf16 bf16x4 __attribute__((ext_vector_type(4)));
typedef float floatx4 __attribute__((ext_vector_type(4)));

// ordered-uint encoding for float atomic min/max (monotone map)
__device__ __forceinline__ unsigned encf(float f) {
    unsigned u = __float_as_uint(f);
    return (u & 0x80000000u) ? ~u : (u | 0x80000000u);
}
__device__ __forceinline__ float decf(unsigned u) {
    return __uint_as_float((u & 0x80000000u) ? (u ^ 0x80000000u) : ~u);
}

// ---------------- K1: partial u + split Wv + hdru init + hist zero ----------------
__global__ void k_prep(const float* __restrict__ Wq, const float* __restrict__ Wk,
                       const float* __restrict__ Wv, const float* __restrict__ w,
                       float* __restrict__ u_part,
                       __bf16* __restrict__ Wh, __bf16* __restrict__ Wl,
                       unsigned* __restrict__ hdru, int* __restrict__ hist) {
    __shared__ float wl[16];
    int d = threadIdx.x;
    int e0 = blockIdx.x * 16;
    int g = blockIdx.x * 256 + d;                 // 0..4095
    ((int4*)hist)[g*2]     = make_int4(0,0,0,0);  // zero BB*NB ints (32768)
    ((int4*)hist)[g*2 + 1] = make_int4(0,0,0,0);
    if (blockIdx.x == 0 && d < 8) hdru[d] = (d & 1) ? 0u : 0xFFFFFFFFu;
    if (d < 16) wl[d] = w[e0 + d];
    __syncthreads();
    float aq = 0.f, ak = 0.f;
    #pragma unroll
    for (int j = 0; j < 16; ++j) {
        float we = wl[j];
        aq = fmaf(Wq[(size_t)(e0 + j)*DD + d], we, aq);
        ak = fmaf(Wk[(size_t)(e0 + j)*DD + d], we, ak);
        float wv = Wv[(size_t)(e0 + j)*DD + d];
        __bf16 h = (__bf16)wv;
        Wh[(size_t)(e0 + j)*DD + d] = h;
        Wl[(size_t)(e0 + j)*DD + d] = (__bf16)(wv - (float)h);
    }
    u_part[(size_t)blockIdx.x*512 + d]       = aq;
    u_part[(size_t)blockIdx.x*512 + DD + d]  = ak;
}

// ---------------- K2: V = x @ Wv^T split-bf16 MFMA (r2-core, r5 epilogue — verified) ----------------
__global__ void __launch_bounds__(256) k_gemm_mfma(
        const float* __restrict__ x,
        const __bf16* __restrict__ Wh, const __bf16* __restrict__ Wl,
        const float* __restrict__ u_part, const float* __restrict__ bmlp,
        float* __restrict__ V, float* __restrict__ a, float* __restrict__ c,
        unsigned* __restrict__ hdru) {
    __shared__ __bf16 Ah[2][32*40];
    __shared__ __bf16 Al[2][32*40];
    __shared__ float4 ul[128];
    __shared__ float pros[512];
    const int tid = threadIdx.x;
    const int wave = tid >> 6, lane = tid & 63;
    const int rowBase = blockIdx.x * 32;
    const int colBase = blockIdx.y * 128;
    const int quad = lane >> 4, l16 = lane & 15;
    const int srow = tid >> 3, skq = (tid & 7) * 4;
    const bool doproj = (blockIdx.y == 0);

    if (doproj && tid < 128) {
        float4 s = make_float4(0.f, 0.f, 0.f, 0.f);
        #pragma unroll
        for (int g = 0; g < 16; ++g) {
            float4 p = *(const float4*)(u_part + (size_t)g*512 + tid*4);
            s.x += p.x; s.y += p.y; s.z += p.z; s.w += p.w;
        }
        ul[tid] = s;
    }
    __syncthreads();

    floatx4 acc[2][2];
    #pragma unroll
    for (int rt = 0; rt < 2; ++rt)
        #pragma unroll
        for (int ct = 0; ct < 2; ++ct)
            acc[rt][ct] = (floatx4){0.f, 0.f, 0.f, 0.f};
    float aq = 0.f, ak = 0.f;

    const float* xrow = x + (size_t)(rowBase + srow)*DD + skq;

    {
        float4 xv = *(const float4*)xrow;
        __bf16 h0 = (__bf16)xv.x, h1 = (__bf16)xv.y, h2 = (__bf16)xv.z, h3 = (__bf16)xv.w;
        bf16x4 hv = {h0, h1, h2, h3};
        bf16x4 lv = {(__bf16)(xv.x - (float)h0), (__bf16)(xv.y - (float)h1),
                     (__bf16)(xv.z - (float)h2), (__bf16)(xv.w - (float)h3)};
        *(bf16x4*)&Ah[0][srow*40 + skq] = hv;
        *(bf16x4*)&Al[0][srow*40 + skq] = lv;
        if (doproj) {
            float4 q4 = ul[(tid & 7)];
            float4 k4 = ul[64 + (tid & 7)];
            aq = fmaf(xv.x, q4.x, fmaf(xv.y, q4.y, fmaf(xv.z, q4.z, fmaf(xv.w, q4.w, aq))));
            ak = fmaf(xv.x, k4.x, fmaf(xv.y, k4.y, fmaf(xv.z, k4.z, fmaf(xv.w, k4.w, ak))));
        }
    }
    __syncthreads();

    for (int t = 0; t < 8; ++t) {
        const int k0 = t * 32;
        const int cur = t & 1;
        float4 xv;
        if (t < 7) xv = *(const float4*)(xrow + k0 + 32);
        bf16x8 ah[2], al[2];
        #pragma unroll
        for (int rt = 0; rt < 2; ++rt) {
            int m = rt*16 + l16;
            ah[rt] = *(bf16x8*)&Ah[cur][m*40 + quad*8];
            al[rt] = *(bf16x8*)&Al[cur][m*40 + quad*8];
        }
        if (t < 7) {
            __bf16 h0 = (__bf16)xv.x, h1 = (__bf16)xv.y, h2 = (__bf16)xv.z, h3 = (__bf16)xv.w;
            bf16x4 hv = {h0, h1, h2, h3};
            bf16x4 lv = {(__bf16)(xv.x - (float)h0), (__bf16)(xv.y - (float)h1),
                         (__bf16)(xv.z - (float)h2), (__bf16)(xv.w - (float)h3)};
            *(bf16x4*)&Ah[cur^1][srow*40 + skq] = hv;
            *(bf16x4*)&Al[cur^1][srow*40 + skq] = lv;
            if (doproj) {
                float4 q4 = ul[((k0 + 32) >> 2) + (tid & 7)];
                float4 k4 = ul[64 + ((k0 + 32) >> 2) + (tid & 7)];
                aq = fmaf(xv.x, q4.x, fmaf(xv.y, q4.y, fmaf(xv.z, q4.z, fmaf(xv.w, q4.w, aq))));
                ak = fmaf(xv.x, k4.x, fmaf(xv.y, k4.y, fmaf(xv.z, k4.z, fmaf(xv.w, k4.w, ak))));
            }
        }
        __syncthreads();
        #pragma unroll
        for (int ct = 0; ct < 2; ++ct) {
            int n = colBase + wave*32 + ct*16 + l16;
            bf16x8 bh = *(const bf16x8*)(Wh + (size_t)n*DD + k0 + quad*8);
            bf16x8 bl = *(const bf16x8*)(Wl + (size_t)n*DD + k0 + quad*8);
            #pragma unroll
            for (int rt = 0; rt < 2; ++rt) {
                acc[rt][ct] = __builtin_amdgcn_mfma_f32_16x16x32_bf16(ah[rt], bh, acc[rt][ct], 0, 0, 0);
                acc[rt][ct] = __builtin_amdgcn_mfma_f32_16x16x32_bf16(ah[rt], bl, acc[rt][ct], 0, 0, 0);
                acc[rt][ct] = __builtin_amdgcn_mfma_f32_16x16x32_bf16(al[rt], bh, acc[rt][ct], 0, 0, 0);
            }
        }
    }
    #pragma unroll
    for (int rt = 0; rt < 2; ++rt)
        #pragma unroll
        for (int ct = 0; ct < 2; ++ct)
            #pragma unroll
            for (int i = 0; i < 4; ++i) {
                int row = rowBase + rt*16 + quad*4 + i;
                int col = colBase + wave*32 + ct*16 + l16;
                V[(size_t)row*DD + col] = acc[rt][ct][i];
            }
    if (doproj) {
        __syncthreads();
        pros[tid] = aq;
        pros[256 + tid] = ak;
        __syncthreads();
        if (tid < 32) {
            float sa = 0.f, sc = 0.f;
            #pragma unroll
            for (int j = 0; j < 8; ++j) {
                sa += pros[tid*8 + j];
                sc += pros[256 + tid*8 + j];
            }
            a[rowBase + tid] = sa + bmlp[0];
            c[rowBase + tid] = sc;
            float mn = sc, mx = sc;
            #pragma unroll
            for (int off = 16; off > 0; off >>= 1) {
                mn = fminf(mn, __shfl_down(mn, off));
                mx = fmaxf(mx, __shfl_down(mx, off));
            }
            if (tid == 0) {
                int bb = rowBase >> 12;
                atomicMin(&hdru[bb*2 + 0], encf(mn));
                atomicMax(&hdru[bb*2 + 1], encf(mx));
            }
        }
    }
}

// ---------------- K3a: global histogram (16 wide blocks, low-contention atomics) ----------------
__global__ void __launch_bounds__(256) k_hist(const float* __restrict__ c,
        const unsigned* __restrict__ hdru, int* __restrict__ hist) {
    const int b = blockIdx.y;
    const int gt = blockIdx.x * 256 + threadIdx.x;    // 0..1023
    float4 cv = ((const float4*)(c + (size_t)b*LL))[gt];
    float cw[4] = {cv.x, cv.y, cv.z, cv.w};
    float cmin = decf(hdru[b*2 + 0]);
    float cmax = decf(hdru[b*2 + 1]);
    float scale = (float)NB / fmaxf(cmax - cmin, 1e-20f);
    #pragma unroll
    for (int u = 0; u < 4; ++u) {
        int bi = (int)((cw[u] - cmin) * scale);
        bi = bi < 0 ? 0 : (bi > NB-1 ? NB-1 : bi);
        atomicAdd(&hist[(size_t)b*NB + bi], 1);
    }
}

// ---------------- K3b: prefix over 8192 bins -> binstart; rebase hist for scatter ----------------
__global__ void __launch_bounds__(1024) k_pfx(int* __restrict__ hist,
        const unsigned* __restrict__ hdru,
        int* __restrict__ binstart_g, float* __restrict__ hdrf) {
    __shared__ int scri[16];
    const int b = blockIdx.x, tid = threadIdx.x;
    const int wave = tid >> 6, lane = tid & 63;
    int4 h0 = ((const int4*)(hist + (size_t)b*NB))[tid*2];
    int4 h1 = ((const int4*)(hist + (size_t)b*NB))[tid*2 + 1];
    int h[8] = {h0.x, h0.y, h0.z, h0.w, h1.x, h1.y, h1.z, h1.w};
    int loc[8]; int base = 0;
    #pragma unroll
    for (int j = 0; j < 8; ++j) { loc[j] = base; base += h[j]; }
    int incl = base;
    #pragma unroll
    for (int off = 1; off < 64; off <<= 1) {
        int t = __shfl_up(incl, off);
        if (lane >= off) incl += t;
    }
    if (lane == 63) scri[wave] = incl;
    __syncthreads();
    if (wave == 0) {
        int v = (lane < 16) ? scri[lane] : 0;
        int s = v;
        #pragma unroll
        for (int off = 1; off < 16; off <<= 1) {
            int t = __shfl_up(s, off);
            if (lane >= off) s += t;
        }
        if (lane < 16) scri[lane] = s - v;
    }
    __syncthreads();
    int thread_excl = (incl - base) + scri[wave];
    #pragma unroll
    for (int j = 0; j < 8; ++j) {
        int bs = thread_excl + loc[j];
        binstart_g[(size_t)b*(NB+2) + tid*8 + j] = bs;
        hist[(size_t)b*NB + tid*8 + j] = bs;       // rebase for k_scat ranks
    }
    if (tid == 0) {
        binstart_g[(size_t)b*(NB+2) + NB]     = LL;
        binstart_g[(size_t)b*(NB+2) + NB + 1] = LL;
        float cmin = decf(hdru[b*2 + 0]);
        float cmax = decf(hdru[b*2 + 1]);
        hdrf[b*2 + 0] = cmin;
        hdrf[b*2 + 1] = (float)NB / fmaxf(cmax - cmin, 1e-20f);
    }
}

// ---------------- K3c: scatter by rank (global atomics; intra-bin order nondet as in r0) ----------------
__global__ void __launch_bounds__(256) k_scat(const float* __restrict__ c,
        const unsigned* __restrict__ hdru, int* __restrict__ hist,
        int* __restrict__ perm, float* __restrict__ c_sorted,
        float* __restrict__ e_sorted) {
    const int b = blockIdx.y;
    const int gt = blockIdx.x * 256 + threadIdx.x;    // 0..1023
    float4 cv = ((const float4*)(c + (size_t)b*LL))[gt];
    float cw[4] = {cv.x, cv.y, cv.z, cv.w};
    float cmin = decf(hdru[b*2 + 0]);
    float cmax = decf(hdru[b*2 + 1]);
    float scale = (float)NB / fmaxf(cmax - cmin, 1e-20f);
    #pragma unroll
    for (int u = 0; u < 4; ++u) {
        int bi = (int)((cw[u] - cmin) * scale);
        bi = bi < 0 ? 0 : (bi > NB-1 ? NB-1 : bi);
        int r = atomicAdd(&hist[(size_t)b*NB + bi], 1);
        perm[(size_t)b*LL + r] = gt*4 + u;
        c_sorted[(size_t)b*LL + r] = cw[u];
        e_sorted[(size_t)b*LL + r] = expf(cmin - cw[u]);
    }
}

// ---------------- K4: merged SE-scan (blocks 0..3) + chunked V prefix (blocks 4..131) — r6-verified ----------------
__global__ void __launch_bounds__(1024) k_mid(
        const int* __restrict__ perm, const float* __restrict__ e_sorted,
        const float* __restrict__ V,
        float* __restrict__ SE,
        float* __restrict__ Pl, float* __restrict__ Pel,
        float* __restrict__ Tp, float* __restrict__ Te)
{
    __shared__ float scrf[64];
    __shared__ int   pj_l[4][CHUNK];
    __shared__ float pe_l[4][CHUNK];
    const int bid = blockIdx.x, tid = threadIdx.x;
    if (bid < BB) {
        const int b = bid, wave = tid >> 6, lane = tid & 63;
        float4 ev = ((const float4*)(e_sorted + (size_t)b*LL))[tid];
        float ew[4] = {ev.x, ev.y, ev.z, ev.w};
        float le[4]; float s0 = 0.f;
        #pragma unroll
        for (int u = 0; u < 4; ++u) { le[u] = s0; s0 += ew[u]; }
        float fincl = s0;
        #pragma unroll
        for (int off = 1; off < 64; off <<= 1) {
            float tt = __shfl_up(fincl, off);
            if (lane >= off) fincl += tt;
        }
        if (lane == 63) scrf[wave] = fincl;
        __syncthreads();
        if (wave == 0) {
            float v = (lane < 16) ? scrf[lane] : 0.f;
            float s = v;
            #pragma unroll
            for (int off = 1; off < 16; off <<= 1) {
                float tt = __shfl_up(s, off);
                if (lane >= off) s += tt;
            }
            if (lane < 16) scrf[lane] = s - v;
        }
        __syncthreads();
        float texcl = (fincl - s0) + scrf[wave];
        #pragma unroll
        for (int u = 0; u < 4; ++u)
            SE[(size_t)b*(LL+1) + tid*4 + u] = texcl + le[u];
        if (tid == 1023) SE[(size_t)b*(LL+1) + LL] = texcl + s0;
    } else {
        const int task = bid - BB;              // 0..127
        const int sub = tid >> 8, d = tid & 255;
        const int chunk = task*4 + sub;         // 0..511
        const int b = chunk >> 7, q = chunk & (NC-1);
        if (d < CHUNK) {
            pj_l[sub][d] = perm[(size_t)b*LL + q*CHUNK + d];
            pe_l[sub][d] = e_sorted[(size_t)b*LL + q*CHUNK + d];
        }
        __syncthreads();
        float vr[CHUNK];
        #pragma unroll
        for (int r = 0; r < CHUNK; ++r)
            vr[r] = V[((size_t)b*LL + pj_l[sub][r])*DD + d];
        float acc = 0.f, acce = 0.f;
        size_t kb = (size_t)b*LL + (size_t)q*CHUNK;
        #pragma unroll
        for (int r = 0; r < CHUNK; ++r) {
            size_t o = (kb + r)*DD + d;
            Pl[o]  = acc;
            Pel[o] = acce;
            acc += vr[r];
            acce = fmaf(pe_l[sub][r], vr[r], acce);
        }
        size_t to = ((size_t)b*NC + q)*DD + d;
        Tp[to] = acc;
        Te[to] = acce;
    }
}

// ---------------- K5: chunk bases (r0 exact) ----------------
__global__ void k_base(const float* __restrict__ Tp, const float* __restrict__ Te,
        float* __restrict__ baseP, float* __restrict__ basePe) {
    int q = blockIdx.x, b = blockIdx.y, d = threadIdx.x;
    float acc = 0.f, acce = 0.f;
    #pragma unroll 8
    for (int i = 0; i < q; ++i) {
        size_t ti = ((size_t)b*NC + i) * DD + d;
        acc += Tp[ti]; acce += Te[ti];
    }
    size_t o = ((size_t)b*(NC+1) + q) * DD + d;
    baseP[o] = acc; basePe[o] = acce;
}

// ---------------- K6: per-row output, O(1) bin lookup + exact boundary fix (r0 exact) ----------------
__global__ void k_out(const float* __restrict__ a, const float* __restrict__ hdrf,
                      const int* __restrict__ binstart,
                      const float* __restrict__ c_sorted, const float* __restrict__ e_sorted,
                      const int* __restrict__ perm, const float* __restrict__ V,
                      const float* __restrict__ SE,
                      const float* __restrict__ Pl, const float* __restrict__ Pel,
                      const float* __restrict__ baseP, const float* __restrict__ basePe,
                      float* __restrict__ out) {
    int row = blockIdx.x * 4 + (threadIdx.x >> 6);
    int lane = threadIdx.x & 63;
    int b = row >> 12;
    float ai = a[row];
    float cmin = hdrf[b*2 + 0], scale = hdrf[b*2 + 1];
    float t = (ai - cmin) * scale;
    int ib = t < 0.f ? 0 : (t >= (float)NB ? NB : (int)t);
    int k    = binstart[(size_t)b*(NB+2) + ib];
    int kend = binstart[(size_t)b*(NB+2) + ib + 1];
    float alpha = expf(cmin - ai);
    float Z = fmaf(alpha, (float)(LL - k), SE[(size_t)b*(LL+1) + k]);
    size_t db = (size_t)lane * 4;
    size_t totoff = ((size_t)b * (NC+1) + NC) * DD + db;
    float4 ptot  = *(const float4*)(baseP  + totoff);
    float4 pk, pek;
    if (k < LL) {
        int q = k >> 5;
        size_t po = ((size_t)b * LL + k) * DD + db;
        size_t bo = ((size_t)b * (NC+1) + q) * DD + db;
        float4 pl = *(const float4*)(Pl    + po);
        float4 bp = *(const float4*)(baseP + bo);
        float4 pe = *(const float4*)(Pel    + po);
        float4 be = *(const float4*)(basePe + bo);
        pk.x = pl.x + bp.x; pk.y = pl.y + bp.y; pk.z = pl.z + bp.z; pk.w = pl.w + bp.w;
        pek.x = pe.x + be.x; pek.y = pe.y + be.y; pek.z = pe.z + be.z; pek.w = pe.w + be.w;
    } else {
        pk = ptot;
        pek = *(const float4*)(basePe + totoff);
    }
    float4 num;
    num.x = fmaf(alpha, ptot.x - pk.x, pek.x);
    num.y = fmaf(alpha, ptot.y - pk.y, pek.y);
    num.z = fmaf(alpha, ptot.z - pk.z, pek.z);
    num.w = fmaf(alpha, ptot.w - pk.w, pek.w);
    for (int r = k; r < kend; ++r) {
        float cr = c_sorted[(size_t)b*LL + r];
        if (cr < ai) {
            float w = e_sorted[(size_t)b*LL + r] - alpha;
            int j = perm[(size_t)b*LL + r];
            float4 v = *(const float4*)(V + ((size_t)b*LL + j) * DD + db);
            num.x = fmaf(w, v.x, num.x);
            num.y = fmaf(w, v.y, num.y);
            num.z = fmaf(w, v.z, num.z);
            num.w = fmaf(w, v.w, num.w);
            Z += w;
        }
    }
    float invZ = 1.f / Z;
    float4 o;
    o.x = num.x * invZ; o.y = num.y * invZ; o.z = num.z * invZ; o.w = num.w * invZ;
    *(float4*)(out + (size_t)row * DD + db) = o;
}

extern "C" void kernel_launch(void* const* d_in, const int* in_sizes, int n_in,
                              void* d_out, int out_size, void* d_ws, size_t ws_size,
                              hipStream_t stream) {
    const float* x  = (const float*)d_in[0];
    const float* Wq = (const float*)d_in[1];
    const float* Wk = (const float*)d_in[2];
    const float* Wv = (const float*)d_in[3];
    const float* wm = (const float*)d_in[4];
    const float* bm = (const float*)d_in[5];
    float* out = (float*)d_out;
    float* ws = (float*)d_ws;

    size_t off = 0;
    auto alloc = [&](size_t n) {      // n in floats
        float* p = ws + off;
        off += (n + 255) & ~(size_t)255;
        return p;
    };
    float* u_part   = alloc(16*512);
    float* a        = alloc(NROWS);
    float* c        = alloc(NROWS);
    float* c_sorted = alloc(NROWS);
    float* e_sorted = alloc(NROWS);
    float* SE       = alloc((size_t)BB*(LL+1));
    int*   perm     = (int*)alloc(NROWS);
    int*   binstart = (int*)alloc((size_t)BB*(NB+2));
    int*   hist     = (int*)alloc((size_t)BB*NB);
    float* hdrf     = alloc(2*BB);
    unsigned* hdru  = (unsigned*)alloc(2*BB);
    float* V        = alloc((size_t)NROWS*DD);
    float* Pl       = alloc((size_t)NROWS*DD);
    float* Pel      = alloc((size_t)NROWS*DD);
    float* Tp       = alloc((size_t)BB*NC*DD);
    float* Te       = alloc((size_t)BB*NC*DD);
    float* baseP    = alloc((size_t)BB*(NC+1)*DD);
    float* basePe   = alloc((size_t)BB*(NC+1)*DD);
    __bf16* Wh      = (__bf16*)alloc((size_t)DD*DD/2);
    __bf16* Wl      = (__bf16*)alloc((size_t)DD*DD/2);

    hipLaunchKernelGGL(k_prep, dim3(16), dim3(DD), 0, stream,
                       Wq, Wk, Wv, wm, u_part, Wh, Wl, hdru, hist);
    hipLaunchKernelGGL(k_gemm_mfma, dim3(NROWS/32, 2), dim3(256), 0, stream,
                       x, Wh, Wl, u_part, bm, V, a, c, hdru);
    hipLaunchKernelGGL(k_hist, dim3(4, BB), dim3(256), 0, stream,
                       c, hdru, hist);
    hipLaunchKernelGGL(k_pfx, dim3(BB), dim3(1024), 0, stream,
                       hist, hdru, binstart, hdrf);
    hipLaunchKernelGGL(k_scat, dim3(4, BB), dim3(256), 0, stream,
                       c, hdru, hist, perm, c_sorted, e_sorted);
    hipLaunchKernelGGL(k_mid, dim3(BB + NC*BB/4), dim3(1024), 0, stream,
                       perm, e_sorted, V, SE, Pl, Pel, Tp, Te);
    hipLaunchKernelGGL(k_base, dim3(NC+1, BB), dim3(256), 0, stream,
                       Tp, Te, baseP, basePe);
    hipLaunchKernelGGL(k_out, dim3(NROWS/4), dim3(256), 0, stream,
                       a, hdrf, binstart, c_sorted, e_sorted, perm, V,
                       SE, Pl, Pel, baseP, basePe, out);
}

// Round 8
// 144.628 us; speedup vs baseline: 1.3144x; 1.0461x over previous
//
#include <hip/hip_runtime.h>
#include <math.h>

#define BB 4
#define LL 4096
#define DD 256
#define NROWS (BB*LL)      // 16384
#define CHUNK 32
#define NC (LL/CHUNK)      // 128
#define NB 8192            // counting-sort bins

typedef __bf16 bf16x8 __attribute__((ext_vector_type(8)));
typedef __bf16 bf16x4 __attribute__((ext_vector_type(4)));
typedef float floatx4 __attribute__((ext_vector_type(4)));

// ordered-uint encoding for float atomic min/max (monotone map)
__device__ __forceinline__ unsigned encf(float f) {
    unsigned u = __float_as_uint(f);
    return (u & 0x80000000u) ? ~u : (u | 0x80000000u);
}
__device__ __forceinline__ float decf(unsigned u) {
    return __uint_as_float((u & 0x80000000u) ? (u ^ 0x80000000u) : ~u);
}

// ---------------- K1: partial u = {Wq^T w, Wk^T w} + split Wv + hdru init ----------------
__global__ void k_prep(const float* __restrict__ Wq, const float* __restrict__ Wk,
                       const float* __restrict__ Wv, const float* __restrict__ w,
                       float* __restrict__ u_part,
                       __bf16* __restrict__ Wh, __bf16* __restrict__ Wl,
                       unsigned* __restrict__ hdru) {
    __shared__ float wl[16];
    int d = threadIdx.x;
    int e0 = blockIdx.x * 16;
    if (blockIdx.x == 0 && d < 8) hdru[d] = (d & 1) ? 0u : 0xFFFFFFFFu;
    if (d < 16) wl[d] = w[e0 + d];
    __syncthreads();
    float aq = 0.f, ak = 0.f;
    #pragma unroll
    for (int j = 0; j < 16; ++j) {
        float we = wl[j];
        aq = fmaf(Wq[(size_t)(e0 + j)*DD + d], we, aq);
        ak = fmaf(Wk[(size_t)(e0 + j)*DD + d], we, ak);
        float wv = Wv[(size_t)(e0 + j)*DD + d];
        __bf16 h = (__bf16)wv;
        Wh[(size_t)(e0 + j)*DD + d] = h;
        Wl[(size_t)(e0 + j)*DD + d] = (__bf16)(wv - (float)h);
    }
    u_part[(size_t)blockIdx.x*512 + d]       = aq;
    u_part[(size_t)blockIdx.x*512 + DD + d]  = ak;
}

// ---------------- K2: V = x @ Wv^T split-bf16 MFMA (r7-verified, minmax epilogue) ----------------
__global__ void __launch_bounds__(256) k_gemm_mfma(
        const float* __restrict__ x,
        const __bf16* __restrict__ Wh, const __bf16* __restrict__ Wl,
        const float* __restrict__ u_part, const float* __restrict__ bmlp,
        float* __restrict__ V, float* __restrict__ a, float* __restrict__ c,
        unsigned* __restrict__ hdru) {
    __shared__ __bf16 Ah[2][32*40];
    __shared__ __bf16 Al[2][32*40];
    __shared__ float4 ul[128];
    __shared__ float pros[512];
    const int tid = threadIdx.x;
    const int wave = tid >> 6, lane = tid & 63;
    const int rowBase = blockIdx.x * 32;
    const int colBase = blockIdx.y * 128;
    const int quad = lane >> 4, l16 = lane & 15;
    const int srow = tid >> 3, skq = (tid & 7) * 4;
    const bool doproj = (blockIdx.y == 0);

    if (doproj && tid < 128) {
        float4 s = make_float4(0.f, 0.f, 0.f, 0.f);
        #pragma unroll
        for (int g = 0; g < 16; ++g) {
            float4 p = *(const float4*)(u_part + (size_t)g*512 + tid*4);
            s.x += p.x; s.y += p.y; s.z += p.z; s.w += p.w;
        }
        ul[tid] = s;
    }
    __syncthreads();

    floatx4 acc[2][2];
    #pragma unroll
    for (int rt = 0; rt < 2; ++rt)
        #pragma unroll
        for (int ct = 0; ct < 2; ++ct)
            acc[rt][ct] = (floatx4){0.f, 0.f, 0.f, 0.f};
    float aq = 0.f, ak = 0.f;

    const float* xrow = x + (size_t)(rowBase + srow)*DD + skq;

    {
        float4 xv = *(const float4*)xrow;
        __bf16 h0 = (__bf16)xv.x, h1 = (__bf16)xv.y, h2 = (__bf16)xv.z, h3 = (__bf16)xv.w;
        bf16x4 hv = {h0, h1, h2, h3};
        bf16x4 lv = {(__bf16)(xv.x - (float)h0), (__bf16)(xv.y - (float)h1),
                     (__bf16)(xv.z - (float)h2), (__bf16)(xv.w - (float)h3)};
        *(bf16x4*)&Ah[0][srow*40 + skq] = hv;
        *(bf16x4*)&Al[0][srow*40 + skq] = lv;
        if (doproj) {
            float4 q4 = ul[(tid & 7)];
            float4 k4 = ul[64 + (tid & 7)];
            aq = fmaf(xv.x, q4.x, fmaf(xv.y, q4.y, fmaf(xv.z, q4.z, fmaf(xv.w, q4.w, aq))));
            ak = fmaf(xv.x, k4.x, fmaf(xv.y, k4.y, fmaf(xv.z, k4.z, fmaf(xv.w, k4.w, ak))));
        }
    }
    __syncthreads();

    for (int t = 0; t < 8; ++t) {
        const int k0 = t * 32;
        const int cur = t & 1;
        float4 xv;
        if (t < 7) xv = *(const float4*)(xrow + k0 + 32);
        bf16x8 ah[2], al[2];
        #pragma unroll
        for (int rt = 0; rt < 2; ++rt) {
            int m = rt*16 + l16;
            ah[rt] = *(bf16x8*)&Ah[cur][m*40 + quad*8];
            al[rt] = *(bf16x8*)&Al[cur][m*40 + quad*8];
        }
        if (t < 7) {
            __bf16 h0 = (__bf16)xv.x, h1 = (__bf16)xv.y, h2 = (__bf16)xv.z, h3 = (__bf16)xv.w;
            bf16x4 hv = {h0, h1, h2, h3};
            bf16x4 lv = {(__bf16)(xv.x - (float)h0), (__bf16)(xv.y - (float)h1),
                         (__bf16)(xv.z - (float)h2), (__bf16)(xv.w - (float)h3)};
            *(bf16x4*)&Ah[cur^1][srow*40 + skq] = hv;
            *(bf16x4*)&Al[cur^1][srow*40 + skq] = lv;
            if (doproj) {
                float4 q4 = ul[((k0 + 32) >> 2) + (tid & 7)];
                float4 k4 = ul[64 + ((k0 + 32) >> 2) + (tid & 7)];
                aq = fmaf(xv.x, q4.x, fmaf(xv.y, q4.y, fmaf(xv.z, q4.z, fmaf(xv.w, q4.w, aq))));
                ak = fmaf(xv.x, k4.x, fmaf(xv.y, k4.y, fmaf(xv.z, k4.z, fmaf(xv.w, k4.w, ak))));
            }
        }
        __syncthreads();
        #pragma unroll
        for (int ct = 0; ct < 2; ++ct) {
            int n = colBase + wave*32 + ct*16 + l16;
            bf16x8 bh = *(const bf16x8*)(Wh + (size_t)n*DD + k0 + quad*8);
            bf16x8 bl = *(const bf16x8*)(Wl + (size_t)n*DD + k0 + quad*8);
            #pragma unroll
            for (int rt = 0; rt < 2; ++rt) {
                acc[rt][ct] = __builtin_amdgcn_mfma_f32_16x16x32_bf16(ah[rt], bh, acc[rt][ct], 0, 0, 0);
                acc[rt][ct] = __builtin_amdgcn_mfma_f32_16x16x32_bf16(ah[rt], bl, acc[rt][ct], 0, 0, 0);
                acc[rt][ct] = __builtin_amdgcn_mfma_f32_16x16x32_bf16(al[rt], bh, acc[rt][ct], 0, 0, 0);
            }
        }
    }
    #pragma unroll
    for (int rt = 0; rt < 2; ++rt)
        #pragma unroll
        for (int ct = 0; ct < 2; ++ct)
            #pragma unroll
            for (int i = 0; i < 4; ++i) {
                int row = rowBase + rt*16 + quad*4 + i;
                int col = colBase + wave*32 + ct*16 + l16;
                V[(size_t)row*DD + col] = acc[rt][ct][i];
            }
    if (doproj) {
        __syncthreads();
        pros[tid] = aq;
        pros[256 + tid] = ak;
        __syncthreads();
        if (tid < 32) {
            float sa = 0.f, sc = 0.f;
            #pragma unroll
            for (int j = 0; j < 8; ++j) {
                sa += pros[tid*8 + j];
                sc += pros[256 + tid*8 + j];
            }
            a[rowBase + tid] = sa + bmlp[0];
            c[rowBase + tid] = sc;
            float mn = sc, mx = sc;
            #pragma unroll
            for (int off = 16; off > 0; off >>= 1) {
                mn = fminf(mn, __shfl_down(mn, off));
                mx = fmaxf(mx, __shfl_down(mx, off));
            }
            if (tid == 0) {
                int bb = rowBase >> 12;
                atomicMin(&hdru[bb*2 + 0], encf(mn));
                atomicMax(&hdru[bb*2 + 1], encf(mx));
            }
        }
    }
}

// ---------------- K3: counting sort, LITE (no minmax phases, no SE) ----------------
// r0's verified sortish structure minus the removed phases: ~6 barrier phases.
__global__ void __launch_bounds__(1024) k_sortl(const float* __restrict__ c,
        const unsigned* __restrict__ hdru,
        int* __restrict__ binstart_g, int* __restrict__ perm,
        float* __restrict__ c_sorted, float* __restrict__ e_sorted,
        float* __restrict__ hdrf) {
    __shared__ int hist[NB];       // 32 KB
    __shared__ int scri[16];
    int b = blockIdx.x, tid = threadIdx.x;
    int wave = tid >> 6, lane = tid & 63;

    float4 cv = ((const float4*)(c + (size_t)b*LL))[tid];
    float cw[4] = {cv.x, cv.y, cv.z, cv.w};
    float cmin = decf(hdru[b*2 + 0]);
    float cmax = decf(hdru[b*2 + 1]);
    float scale = (float)NB / fmaxf(cmax - cmin, 1e-20f);

    ((int4*)hist)[tid] = make_int4(0,0,0,0);
    ((int4*)hist)[tid + 1024] = make_int4(0,0,0,0);
    __syncthreads();

    int bins[4];
    #pragma unroll
    for (int u = 0; u < 4; ++u) {
        int bi = (int)((cw[u] - cmin) * scale);
        bi = bi < 0 ? 0 : (bi > NB-1 ? NB-1 : bi);
        bins[u] = bi;
        atomicAdd(&hist[bi], 1);
    }
    __syncthreads();

    int loc[8]; int base = 0;
    #pragma unroll
    for (int j = 0; j < 8; ++j) { loc[j] = base; base += hist[tid*8 + j]; }
    int incl = base;
    #pragma unroll
    for (int off = 1; off < 64; off <<= 1) {
        int t = __shfl_up(incl, off);
        if (lane >= off) incl += t;
    }
    if (lane == 63) scri[wave] = incl;
    __syncthreads();
    if (wave == 0) {
        int v = (lane < 16) ? scri[lane] : 0;
        int s = v;
        #pragma unroll
        for (int off = 1; off < 16; off <<= 1) {
            int t = __shfl_up(s, off);
            if (lane >= off) s += t;
        }
        if (lane < 16) scri[lane] = s - v;
    }
    __syncthreads();
    int thread_excl = (incl - base) + scri[wave];
    __syncthreads();
    #pragma unroll
    for (int j = 0; j < 8; ++j) {
        int bs = thread_excl + loc[j];
        binstart_g[(size_t)b*(NB+2) + tid*8 + j] = bs;
        hist[tid*8 + j] = bs;
    }
    if (tid == 0) {
        binstart_g[(size_t)b*(NB+2) + NB]     = LL;
        binstart_g[(size_t)b*(NB+2) + NB + 1] = LL;
        hdrf[b*2 + 0] = cmin;
        hdrf[b*2 + 1] = scale;
    }
    __syncthreads();

    #pragma unroll
    for (int u = 0; u < 4; ++u) {
        int i = tid*4 + u;
        int r = atomicAdd(&hist[bins[u]], 1);
        perm[(size_t)b*LL + r] = i;
        c_sorted[(size_t)b*LL + r] = cw[u];
        e_sorted[(size_t)b*LL + r] = expf(cmin - cw[u]);
    }
}

// ---------------- K4: chunked V prefix (r0 exact, q<NC) + SE prefix (q==NC column) ----------------
__global__ void __launch_bounds__(256) k_scan(const float* __restrict__ V,
        const int* __restrict__ perm, const float* __restrict__ e_sorted,
        float* __restrict__ Pl, float* __restrict__ Pel,
        float* __restrict__ Tp, float* __restrict__ Te,
        float* __restrict__ SE) {
    int b = blockIdx.y, q = blockIdx.x;
    int d = threadIdx.x;
    __shared__ int pj[CHUNK];
    __shared__ float pe[CHUNK];
    __shared__ float scrf[8];
    if (q < NC) {
        // ---- r0-verified chunk scan ----
        if (d < CHUNK) {
            pj[d] = perm[(size_t)b*LL + q*CHUNK + d];
            pe[d] = e_sorted[(size_t)b*LL + q*CHUNK + d];
        }
        __syncthreads();
        float vr[CHUNK];
        #pragma unroll
        for (int r = 0; r < CHUNK; ++r)
            vr[r] = V[((size_t)b*LL + pj[r]) * DD + d];
        float acc = 0.f, acce = 0.f;
        size_t kb = (size_t)b*LL + (size_t)q*CHUNK;
        #pragma unroll
        for (int r = 0; r < CHUNK; ++r) {
            size_t o = (kb + r) * DD + d;
            Pl[o]  = acc;
            Pel[o] = acce;
            acc += vr[r];
            acce = fmaf(pe[r], vr[r], acce);
        }
        size_t to = ((size_t)b*NC + q) * DD + d;
        Tp[to] = acc;
        Te[to] = acce;
    } else {
        // ---- SE exclusive prefix of e_sorted over ranks: 256 thr, 16 els/thread ----
        const int wave = d >> 6, lane = d & 63;
        float ew[16];
        #pragma unroll
        for (int v4 = 0; v4 < 4; ++v4) {
            float4 ev = ((const float4*)(e_sorted + (size_t)b*LL))[d*4 + v4];
            ew[v4*4+0] = ev.x; ew[v4*4+1] = ev.y; ew[v4*4+2] = ev.z; ew[v4*4+3] = ev.w;
        }
        float le[16]; float s0 = 0.f;
        #pragma unroll
        for (int u = 0; u < 16; ++u) { le[u] = s0; s0 += ew[u]; }
        float fincl = s0;
        #pragma unroll
        for (int off = 1; off < 64; off <<= 1) {
            float tt = __shfl_up(fincl, off);
            if (lane >= off) fincl += tt;
        }
        if (lane == 63) scrf[wave] = fincl;
        __syncthreads();
        if (wave == 0) {
            float v = (lane < 4) ? scrf[lane] : 0.f;
            float s = v;
            #pragma unroll
            for (int off = 1; off < 4; off <<= 1) {
                float tt = __shfl_up(s, off);
                if (lane >= off) s += tt;
            }
            if (lane < 4) scrf[lane] = s - v;
        }
        __syncthreads();
        float texcl = (fincl - s0) + scrf[wave];
        #pragma unroll
        for (int u = 0; u < 16; ++u)
            SE[(size_t)b*(LL+1) + d*16 + u] = texcl + le[u];
        if (d == 255) SE[(size_t)b*(LL+1) + LL] = texcl + s0;
    }
}

// ---------------- K5: chunk bases (r0 exact) ----------------
__global__ void k_base(const float* __restrict__ Tp, const float* __restrict__ Te,
        float* __restrict__ baseP, float* __restrict__ basePe) {
    int q = blockIdx.x, b = blockIdx.y, d = threadIdx.x;
    float acc = 0.f, acce = 0.f;
    #pragma unroll 8
    for (int i = 0; i < q; ++i) {
        size_t ti = ((size_t)b*NC + i) * DD + d;
        acc += Tp[ti]; acce += Te[ti];
    }
    size_t o = ((size_t)b*(NC+1) + q) * DD + d;
    baseP[o] = acc; basePe[o] = acce;
}

// ---------------- K6: per-row output, O(1) bin lookup + exact boundary fix (r0 exact) ----------------
__global__ void k_out(const float* __restrict__ a, const float* __restrict__ hdrf,
                      const int* __restrict__ binstart,
                      const float* __restrict__ c_sorted, const float* __restrict__ e_sorted,
                      const int* __restrict__ perm, const float* __restrict__ V,
                      const float* __restrict__ SE,
                      const float* __restrict__ Pl, const float* __restrict__ Pel,
                      const float* __restrict__ baseP, const float* __restrict__ basePe,
                      float* __restrict__ out) {
    int row = blockIdx.x * 4 + (threadIdx.x >> 6);
    int lane = threadIdx.x & 63;
    int b = row >> 12;
    float ai = a[row];
    float cmin = hdrf[b*2 + 0], scale = hdrf[b*2 + 1];
    float t = (ai - cmin) * scale;
    int ib = t < 0.f ? 0 : (t >= (float)NB ? NB : (int)t);
    int k    = binstart[(size_t)b*(NB+2) + ib];
    int kend = binstart[(size_t)b*(NB+2) + ib + 1];
    float alpha = expf(cmin - ai);
    float Z = fmaf(alpha, (float)(LL - k), SE[(size_t)b*(LL+1) + k]);
    size_t db = (size_t)lane * 4;
    size_t totoff = ((size_t)b * (NC+1) + NC) * DD + db;
    float4 ptot  = *(const float4*)(baseP  + totoff);
    float4 pk, pek;
    if (k < LL) {
        int q = k >> 5;
        size_t po = ((size_t)b * LL + k) * DD + db;
        size_t bo = ((size_t)b * (NC+1) + q) * DD + db;
        float4 pl = *(const float4*)(Pl    + po);
        float4 bp = *(const float4*)(baseP + bo);
        float4 pe = *(const float4*)(Pel    + po);
        float4 be = *(const float4*)(basePe + bo);
        pk.x = pl.x + bp.x; pk.y = pl.y + bp.y; pk.z = pl.z + bp.z; pk.w = pl.w + bp.w;
        pek.x = pe.x + be.x; pek.y = pe.y + be.y; pek.z = pe.z + be.z; pek.w = pe.w + be.w;
    } else {
        pk = ptot;
        pek = *(const float4*)(basePe + totoff);
    }
    float4 num;
    num.x = fmaf(alpha, ptot.x - pk.x, pek.x);
    num.y = fmaf(alpha, ptot.y - pk.y, pek.y);
    num.z = fmaf(alpha, ptot.z - pk.z, pek.z);
    num.w = fmaf(alpha, ptot.w - pk.w, pek.w);
    for (int r = k; r < kend; ++r) {
        float cr = c_sorted[(size_t)b*LL + r];
        if (cr < ai) {
            float w = e_sorted[(size_t)b*LL + r] - alpha;
            int j = perm[(size_t)b*LL + r];
            float4 v = *(const float4*)(V + ((size_t)b*LL + j) * DD + db);
            num.x = fmaf(w, v.x, num.x);
            num.y = fmaf(w, v.y, num.y);
            num.z = fmaf(w, v.z, num.z);
            num.w = fmaf(w, v.w, num.w);
            Z += w;
        }
    }
    float invZ = 1.f / Z;
    float4 o;
    o.x = num.x * invZ; o.y = num.y * invZ; o.z = num.z * invZ; o.w = num.w * invZ;
    *(float4*)(out + (size_t)row * DD + db) = o;
}

extern "C" void kernel_launch(void* const* d_in, const int* in_sizes, int n_in,
                              void* d_out, int out_size, void* d_ws, size_t ws_size,
                              hipStream_t stream) {
    const float* x  = (const float*)d_in[0];
    const float* Wq = (const float*)d_in[1];
    const float* Wk = (const float*)d_in[2];
    const float* Wv = (const float*)d_in[3];
    const float* wm = (const float*)d_in[4];
    const float* bm = (const float*)d_in[5];
    float* out = (float*)d_out;
    float* ws = (float*)d_ws;

    size_t off = 0;
    auto alloc = [&](size_t n) {      // n in floats
        float* p = ws + off;
        off += (n + 255) & ~(size_t)255;
        return p;
    };
    float* u_part   = alloc(16*512);
    float* a        = alloc(NROWS);
    float* c        = alloc(NROWS);
    float* c_sorted = alloc(NROWS);
    float* e_sorted = alloc(NROWS);
    float* SE       = alloc((size_t)BB*(LL+1));
    int*   perm     = (int*)alloc(NROWS);
    int*   binstart = (int*)alloc((size_t)BB*(NB+2));
    float* hdrf     = alloc(2*BB);
    unsigned* hdru  = (unsigned*)alloc(2*BB);
    float* V        = alloc((size_t)NROWS*DD);
    float* Pl       = alloc((size_t)NROWS*DD);
    float* Pel      = alloc((size_t)NROWS*DD);
    float* Tp       = alloc((size_t)BB*NC*DD);
    float* Te       = alloc((size_t)BB*NC*DD);
    float* baseP    = alloc((size_t)BB*(NC+1)*DD);
    float* basePe   = alloc((size_t)BB*(NC+1)*DD);
    __bf16* Wh      = (__bf16*)alloc((size_t)DD*DD/2);
    __bf16* Wl      = (__bf16*)alloc((size_t)DD*DD/2);

    hipLaunchKernelGGL(k_prep, dim3(16), dim3(DD), 0, stream,
                       Wq, Wk, Wv, wm, u_part, Wh, Wl, hdru);
    hipLaunchKernelGGL(k_gemm_mfma, dim3(NROWS/32, 2), dim3(256), 0, stream,
                       x, Wh, Wl, u_part, bm, V, a, c, hdru);
    hipLaunchKernelGGL(k_sortl, dim3(BB), dim3(1024), 0, stream,
                       c, hdru, binstart, perm, c_sorted, e_sorted, hdrf);
    hipLaunchKernelGGL(k_scan, dim3(NC+1, BB), dim3(DD), 0, stream,
                       V, perm, e_sorted, Pl, Pel, Tp, Te, SE);
    hipLaunchKernelGGL(k_base, dim3(NC+1, BB), dim3(DD), 0, stream,
                       Tp, Te, baseP, basePe);
    hipLaunchKernelGGL(k_out, dim3(NROWS/4), dim3(256), 0, stream,
                       a, hdrf, binstart, c_sorted, e_sorted, perm, V,
                       SE, Pl, Pel, baseP, basePe, out);
}